// Round 5
// baseline (1482.711 us; speedup 1.0000x reference)
//
#include <hip/hip_runtime.h>
#include <cmath>

#define NFEAT 350
#define DMODEL 512
#define NLAYER 4
#define DSZ 64
#define REG_E 32
#define BATCH 32
#define SEQ 2048
#define MTOK (BATCH * SEQ)      // 65536
#define CLAMP_V 20.0f

#define CHUNK 64
#define NCHUNK (SEQ / CHUNK)    // 32

typedef short bf16x8 __attribute__((ext_vector_type(8)));
typedef float f32x4 __attribute__((ext_vector_type(4)));

__device__ __forceinline__ unsigned short f2b(float v) {
    union { float f; unsigned int u; } x; x.f = v;
    unsigned int r = x.u + 0x7fffu + ((x.u >> 16) & 1u);
    return (unsigned short)(r >> 16);
}
__device__ __forceinline__ float b2f(unsigned short u) {
    union { unsigned int i; float f; } x; x.i = ((unsigned int)u) << 16;
    return x.f;
}
__device__ __forceinline__ unsigned int pack2(float a, float b) {
    return ((unsigned int)f2b(b) << 16) | f2b(a);
}

// ---------------- weight preconvert: dst[n][k] = bf16(src[k][n]), zero-padded ----------------
__global__ __launch_bounds__(256) void tconv_k(const float* __restrict__ src,
                                               unsigned short* __restrict__ dst,
                                               int K, int N, int Kpad) {
    int k = blockIdx.x * 256 + threadIdx.x;
    int n = blockIdx.y;
    if (k >= Kpad) return;
    float v = (k < K && n < N) ? src[(size_t)k * N + n] : 0.f;
    dst[(size_t)n * Kpad + k] = f2b(v);
}

// gates weights: z = l*4+g; src [512][64] -> hi/lo planes [z][64 n][512 k]
__global__ __launch_bounds__(256) void tconv_g_k(const float* __restrict__ wi,
                                                 const float* __restrict__ wf,
                                                 const float* __restrict__ wz,
                                                 const float* __restrict__ wo,
                                                 unsigned short* __restrict__ dstH,
                                                 unsigned short* __restrict__ dstL) {
    int k = blockIdx.x * 256 + threadIdx.x;
    int n = blockIdx.y;
    int z = blockIdx.z;
    int l = z >> 2, g = z & 3;
    const float* src = (g == 0 ? wi : g == 1 ? wf : g == 2 ? wz : wo) + (size_t)l * DMODEL * DSZ;
    float v = src[(size_t)k * DSZ + n];
    unsigned short hi = f2b(v);
    unsigned short lo = f2b(v - b2f(hi));
    dstH[(size_t)z * 32768 + (size_t)n * 512 + k] = hi;
    dstL[(size_t)z * 32768 + (size_t)n * 512 + k] = lo;
}

__global__ __launch_bounds__(1024) void gbias_k(const float* bi, const float* bf_,
                                                const float* bz, const float* bo,
                                                float* __restrict__ gbias) {
    int t = threadIdx.x;                 // 1024 = L*256
    int l = t >> 8, r = t & 255, g = r >> 6, e = r & 63;
    const float* s = (g == 0 ? bi : g == 1 ? bf_ : g == 2 ? bz : bo);
    gbias[t] = s[l * 64 + e];
}

// ---------------- xc = bf16(concat(x, emb[rid], 0)) [MTOK][384] ----------------
__global__ __launch_bounds__(256) void build_xc_k(const float* __restrict__ x,
                                                  const int* __restrict__ rid,
                                                  const float* __restrict__ emb,
                                                  unsigned short* __restrict__ xc) {
    int i = blockIdx.x * 256 + threadIdx.x;      // MTOK*192
    int m = i / 192, p = i - m * 192;
    int k = p * 2;
    float a = 0.f, b = 0.f;
    if (k < 350) {
        const float2 v = *(const float2*)(x + (size_t)m * NFEAT + k);
        a = v.x; b = v.y;
    } else if (k < 382) {
        int r = rid[m];
        const float2 v = *(const float2*)(emb + r * REG_E + (k - 350));
        a = v.x; b = v.y;
    }
    ((unsigned int*)xc)[(size_t)m * 192 + p] = pack2(a, b);
}

// ---------------- generic MFMA GEMM (GRN phase; unchanged from round 4) ----------------
// ALD 0: A bf16 [M][lda]. EPI 0: elu->bf16 | 1: none->bf16 | 3: none->f32
template <int ALD, int EPI>
__global__ __launch_bounds__(256) void mgemm_k(const unsigned short* __restrict__ Ab,
                                               const float* __restrict__ Af,
                                               const unsigned short* __restrict__ Bt,
                                               const float* __restrict__ bias,
                                               float* __restrict__ Cf,
                                               unsigned short* __restrict__ Cb,
                                               const float* __restrict__ muA,
                                               const float* __restrict__ rstdA,
                                               const float* __restrict__ lng,
                                               const float* __restrict__ lnb,
                                               int lda, int ldb, int K, int N, int ldc) {
    __shared__ unsigned short As[128][40];
    __shared__ unsigned short Bs[128][40];
    const int tid = threadIdx.x;
    const int lane = tid & 63;
    const int wave = tid >> 6;
    const int l15 = lane & 15;
    const int quad = lane >> 4;
    const int wm = (wave >> 1) * 64;
    const int wn = (wave & 1) * 64;
    const size_t m0 = (size_t)blockIdx.y * 128;
    const int n0 = blockIdx.x * 128;

    const int sr = tid >> 2;
    const int ku = tid & 3;

    const unsigned short* Br0 = Bt + ((size_t)(n0 + sr)) * ldb + ku * 8;
    const unsigned short* Br1 = Br0 + (size_t)64 * ldb;
    const unsigned short* Ar0 = Ab + (m0 + sr) * (size_t)lda + ku * 8;
    const unsigned short* Ar1 = Ar0 + (size_t)64 * lda;

    f32x4 acc[4][4] = {};

    for (int k0 = 0; k0 < K; k0 += 32) {
        *(uint4*)&As[sr][ku * 8]      = *(const uint4*)(Ar0 + k0);
        *(uint4*)&As[sr + 64][ku * 8] = *(const uint4*)(Ar1 + k0);
        *(uint4*)&Bs[sr][ku * 8]      = *(const uint4*)(Br0 + k0);
        *(uint4*)&Bs[sr + 64][ku * 8] = *(const uint4*)(Br1 + k0);
        __syncthreads();
        bf16x8 af[4], bf[4];
#pragma unroll
        for (int mt = 0; mt < 4; mt++)
            af[mt] = *(const bf16x8*)&As[wm + mt * 16 + l15][quad * 8];
#pragma unroll
        for (int nt = 0; nt < 4; nt++)
            bf[nt] = *(const bf16x8*)&Bs[wn + nt * 16 + l15][quad * 8];
#pragma unroll
        for (int mt = 0; mt < 4; mt++)
#pragma unroll
            for (int nt = 0; nt < 4; nt++)
                acc[mt][nt] = __builtin_amdgcn_mfma_f32_16x16x32_bf16(af[mt], bf[nt], acc[mt][nt], 0, 0, 0);
        __syncthreads();
    }

#pragma unroll
    for (int mt = 0; mt < 4; mt++) {
        int gmb = wm + mt * 16 + quad * 4;
#pragma unroll
        for (int nt = 0; nt < 4; nt++) {
            int gn = n0 + wn + nt * 16 + l15;
            if (gn < N) {
                float bv = bias[gn];
#pragma unroll
                for (int r = 0; r < 4; r++) {
                    size_t gm = m0 + gmb + r;
                    float v = acc[mt][nt][r] + bv;
                    if (EPI == 0) {
                        v = v > 0.f ? v : expm1f(v);
                        Cb[gm * (size_t)ldc + gn] = f2b(v);
                    } else if (EPI == 1) {
                        Cb[gm * (size_t)ldc + gn] = f2b(v);
                    } else {
                        Cf[gm * (size_t)ldc + gn] = v;
                    }
                }
            }
        }
    }
}

// ---------------- gates GEMM: hi/lo split both operands, LN fused, pipelined ----------------
// A = LN(h) f32->bf16 hi/lo in staging; B pre-split planes [256 n][512 k].
// Tile 64m x 128n, grid (2, 1024), 256 threads = 4 waves (2m x 1n split: wm=(w>>1)*32, wn=(w&1)*64).
__global__ __launch_bounds__(256) void ggemm_k(const float* __restrict__ h,
                                               const unsigned short* __restrict__ BtH,
                                               const unsigned short* __restrict__ BtL,
                                               const float* __restrict__ bias,
                                               const float* __restrict__ mu,
                                               const float* __restrict__ rstd,
                                               const float* __restrict__ lng,
                                               const float* __restrict__ lnb,
                                               float* __restrict__ gates) {
    __shared__ unsigned short AsH[64][40];
    __shared__ unsigned short AsL[64][40];
    __shared__ unsigned short BsH[128][40];
    __shared__ unsigned short BsL[128][40];
    const int tid = threadIdx.x;
    const int lane = tid & 63;
    const int wave = tid >> 6;
    const int l15 = lane & 15;
    const int quad = lane >> 4;
    const int wm = (wave >> 1) * 32;
    const int wn = (wave & 1) * 64;
    const size_t m0 = (size_t)blockIdx.y * 64;
    const int n0 = blockIdx.x * 128;

    // A staging: row sr (0..63), 8 elems at ku*8
    const int sr = tid >> 2;
    const int ku = tid & 3;
    const float* Ar = h + (m0 + sr) * (size_t)DMODEL + ku * 8;
    const float muv = mu[m0 + sr];
    const float rsv = rstd[m0 + sr];

    // B staging: row br (0..127), 16 elems at kh
    const int br = tid >> 1;
    const int kh = (tid & 1) * 16;
    const unsigned short* BH = BtH + (size_t)(n0 + br) * 512 + kh;
    const unsigned short* BL = BtL + (size_t)(n0 + br) * 512 + kh;

    // prefetch k0 = 0
    float4 a0 = *(const float4*)(Ar);
    float4 a1 = *(const float4*)(Ar + 4);
    uint4 vh0 = *(const uint4*)(BH);
    uint4 vh1 = *(const uint4*)(BH + 8);
    uint4 vl0 = *(const uint4*)(BL);
    uint4 vl1 = *(const uint4*)(BL + 8);

    f32x4 acc[2][4] = {};

    for (int k0 = 0; k0 < DMODEL; k0 += 32) {
        // LN + hi/lo split of A regs
        {
            float4 g0 = *(const float4*)(lng + k0 + ku * 8);
            float4 g1 = *(const float4*)(lng + k0 + ku * 8 + 4);
            float4 c0 = *(const float4*)(lnb + k0 + ku * 8);
            float4 c1 = *(const float4*)(lnb + k0 + ku * 8 + 4);
            float v[8];
            v[0] = (a0.x - muv) * rsv * g0.x + c0.x;
            v[1] = (a0.y - muv) * rsv * g0.y + c0.y;
            v[2] = (a0.z - muv) * rsv * g0.z + c0.z;
            v[3] = (a0.w - muv) * rsv * g0.w + c0.w;
            v[4] = (a1.x - muv) * rsv * g1.x + c1.x;
            v[5] = (a1.y - muv) * rsv * g1.y + c1.y;
            v[6] = (a1.z - muv) * rsv * g1.z + c1.z;
            v[7] = (a1.w - muv) * rsv * g1.w + c1.w;
            unsigned int hw[4], lw[4];
#pragma unroll
            for (int j = 0; j < 4; j++) {
                unsigned short h0 = f2b(v[2 * j]);
                unsigned short h1 = f2b(v[2 * j + 1]);
                unsigned short l0 = f2b(v[2 * j] - b2f(h0));
                unsigned short l1 = f2b(v[2 * j + 1] - b2f(h1));
                hw[j] = (unsigned int)h0 | ((unsigned int)h1 << 16);
                lw[j] = (unsigned int)l0 | ((unsigned int)l1 << 16);
            }
            *(uint4*)&AsH[sr][ku * 8] = *(uint4*)hw;
            *(uint4*)&AsL[sr][ku * 8] = *(uint4*)lw;
        }
        *(uint4*)&BsH[br][kh]     = vh0;
        *(uint4*)&BsH[br][kh + 8] = vh1;
        *(uint4*)&BsL[br][kh]     = vl0;
        *(uint4*)&BsL[br][kh + 8] = vl1;
        __syncthreads();

        // prefetch next k-tile (overlaps ds_read + MFMA)
        if (k0 + 32 < DMODEL) {
            a0 = *(const float4*)(Ar + k0 + 32);
            a1 = *(const float4*)(Ar + k0 + 36);
            vh0 = *(const uint4*)(BH + k0 + 32);
            vh1 = *(const uint4*)(BH + k0 + 40);
            vl0 = *(const uint4*)(BL + k0 + 32);
            vl1 = *(const uint4*)(BL + k0 + 40);
        }

        bf16x8 ah[2], al[2], bh[4], bl[4];
#pragma unroll
        for (int mt = 0; mt < 2; mt++) {
            ah[mt] = *(const bf16x8*)&AsH[wm + mt * 16 + l15][quad * 8];
            al[mt] = *(const bf16x8*)&AsL[wm + mt * 16 + l15][quad * 8];
        }
#pragma unroll
        for (int nt = 0; nt < 4; nt++) {
            bh[nt] = *(const bf16x8*)&BsH[wn + nt * 16 + l15][quad * 8];
            bl[nt] = *(const bf16x8*)&BsL[wn + nt * 16 + l15][quad * 8];
        }
#pragma unroll
        for (int mt = 0; mt < 2; mt++)
#pragma unroll
            for (int nt = 0; nt < 4; nt++) {
                acc[mt][nt] = __builtin_amdgcn_mfma_f32_16x16x32_bf16(ah[mt], bh[nt], acc[mt][nt], 0, 0, 0);
                acc[mt][nt] = __builtin_amdgcn_mfma_f32_16x16x32_bf16(al[mt], bh[nt], acc[mt][nt], 0, 0, 0);
                acc[mt][nt] = __builtin_amdgcn_mfma_f32_16x16x32_bf16(ah[mt], bl[nt], acc[mt][nt], 0, 0, 0);
            }
        __syncthreads();
    }

#pragma unroll
    for (int mt = 0; mt < 2; mt++) {
        int gmb = wm + mt * 16 + quad * 4;
#pragma unroll
        for (int nt = 0; nt < 4; nt++) {
            int gn = n0 + wn + nt * 16 + l15;
            float bv = bias[gn];
            int g = gn >> 6;
#pragma unroll
            for (int r = 0; r < 4; r++) {
                size_t gm = m0 + gmb + r;
                float v = acc[mt][nt][r] + bv;
                if (g < 2) v = fminf(fmaxf(v, -CLAMP_V), CLAMP_V);
                else if (g == 2) v = tanhf(v);
                else v = 1.f / (1.f + expf(-v));
                gates[gm * 256 + gn] = v;
            }
        }
    }
}

// ---------------- softmax over bf16 logits; writes xw=w*x in-place into xc; emits w last row ----------------
__global__ __launch_bounds__(256) void softmax_xw_k(const unsigned short* __restrict__ logits,
                                                    unsigned short* __restrict__ xc,
                                                    float* __restrict__ out_wlast) {
    int tok = blockIdx.x * 4 + (threadIdx.x >> 6);
    int lane = threadIdx.x & 63;
    const unsigned short* lr = logits + (size_t)tok * NFEAT;
    unsigned short* xr = xc + (size_t)tok * 384;
    float v[6];
    float mx = -1e30f;
#pragma unroll
    for (int i = 0; i < 6; i++) {
        int idx = lane + 64 * i;
        v[i] = (idx < NFEAT) ? b2f(lr[idx]) : -1e30f;
        mx = fmaxf(mx, v[i]);
    }
#pragma unroll
    for (int o = 32; o > 0; o >>= 1) mx = fmaxf(mx, __shfl_xor(mx, o, 64));
    float s = 0.f;
#pragma unroll
    for (int i = 0; i < 6; i++) { v[i] = expf(v[i] - mx); s += v[i]; }
#pragma unroll
    for (int o = 32; o > 0; o >>= 1) s += __shfl_xor(s, o, 64);
    float inv = 1.f / s;
    bool last = ((tok & (SEQ - 1)) == SEQ - 1);
    int b = tok >> 11;
#pragma unroll
    for (int i = 0; i < 6; i++) {
        int idx = lane + 64 * i;
        if (idx < NFEAT) {
            float w = v[i] * inv;
            xr[idx] = f2b(w * b2f(xr[idx]));
            if (last) out_wlast[b * NFEAT + idx] = w;
        } else if (idx < 352) {
            xr[idx] = 0;   // kill emb residue: GEMM2 reads K=352
        }
    }
}

// ---------------- per-token LN stats (mu, rstd) on f32 h ----------------
__global__ __launch_bounds__(256) void ln_stats_k(const float* __restrict__ h,
                                                  float* __restrict__ mu,
                                                  float* __restrict__ rstd) {
    int tok = blockIdx.x * 4 + (threadIdx.x >> 6);
    int lane = threadIdx.x & 63;
    const float* row = h + (size_t)tok * DMODEL;
    float s = 0.f, sq = 0.f;
#pragma unroll
    for (int i = 0; i < 8; i++) {
        float v = row[lane + 64 * i];
        s += v;
        sq += v * v;
    }
#pragma unroll
    for (int o = 32; o > 0; o >>= 1) {
        s += __shfl_xor(s, o, 64);
        sq += __shfl_xor(sq, o, 64);
    }
    if (lane == 0) {
        float m = s * (1.f / DMODEL);
        float var = sq * (1.f / DMODEL) - m * m;
        mu[tok] = m;
        rstd[tok] = rsqrtf(var + 1e-5f);
    }
}

// ================= chunked parallel scan =================
__global__ __launch_bounds__(256) void seg_agg_k(const float* __restrict__ gates,
                                                 float* __restrict__ aggF,
                                                 float* __restrict__ aggL,
                                                 float* __restrict__ aggS) {
    int b = blockIdx.x >> 3;
    int cg = blockIdx.x & 7;
    int chunk = cg * 4 + (threadIdx.x >> 6);
    int e = threadIdx.x & 63;
    const float* gp = gates + ((size_t)b * SEQ + (size_t)chunk * CHUNK) * 256;
    float F = 0.f, L = -1e30f, s = 0.f;
#pragma unroll 4
    for (int t = 0; t < CHUNK; t++) {
        const float* q = gp + (size_t)t * 256;
        float li = q[e], lf = q[64 + e], z = q[128 + e];
        float Ln = fmaxf(L + lf, li);
        s = expf(L + lf - Ln) * s + expf(li - Ln) * z;
        L = Ln;
        F += lf;
    }
    int idx = (b * NCHUNK + chunk) * 64 + e;
    aggF[idx] = F; aggL[idx] = L; aggS[idx] = s;
}

__global__ __launch_bounds__(64) void chunk_scan_k(const float* __restrict__ aggF,
                                                   const float* __restrict__ aggL,
                                                   const float* __restrict__ aggS,
                                                   float* __restrict__ stM,
                                                   float* __restrict__ stC) {
    int b = blockIdx.x;
    int e = threadIdx.x;
    float m = 0.f, c = 0.f;
    for (int k = 0; k < NCHUNK; k++) {
        int idx = (b * NCHUNK + k) * 64 + e;
        stM[idx] = m; stC[idx] = c;
        float F = aggF[idx], L = aggL[idx], s = aggS[idx];
        float mn = fmaxf(m + F, L);
        c = expf(m + F - mn) * c + expf(L - mn) * s;
        m = mn;
    }
}

__global__ __launch_bounds__(256) void replay_k(const float* __restrict__ gates,
                                                const float* __restrict__ stM,
                                                const float* __restrict__ stC,
                                                float* __restrict__ hs) {
    int b = blockIdx.x >> 3;
    int cg = blockIdx.x & 7;
    int chunk = cg * 4 + (threadIdx.x >> 6);
    int e = threadIdx.x & 63;
    int s0 = chunk * CHUNK;
    const float* gp = gates + ((size_t)b * SEQ + s0) * 256;
    float* hp = hs + ((size_t)b * SEQ + s0) * DSZ;
    int idx = (b * NCHUNK + chunk) * 64 + e;
    float m = stM[idx], c = stC[idx];
#pragma unroll 4
    for (int t = 0; t < CHUNK; t++) {
        const float* q = gp + (size_t)t * 256;
        float li = q[e], lf = q[64 + e], z = q[128 + e], o = q[192 + e];
        float mlf = m + lf;
        float mn = fmaxf(mlf, li);
        c = expf(mlf - mn) * c + expf(li - mn) * z;
        m = mn;
        hp[(size_t)t * DSZ + e] = o * tanhf(c);
    }
}

// ---------------- out-proj + residual + LN (h f32 in-place) + mu/rstd for next layer ----------------
__global__ __launch_bounds__(256) void outproj_k(const float* __restrict__ hs,
                                                 const float* __restrict__ wp,
                                                 const float* __restrict__ bp,
                                                 const float* __restrict__ nmg,
                                                 const float* __restrict__ nmb,
                                                 float* __restrict__ h,
                                                 float* __restrict__ mu,
                                                 float* __restrict__ rstd) {
    __shared__ float shs[16][DSZ];
    __shared__ float swp[16][DMODEL];
    int wv = threadIdx.x >> 6;
    int lane = threadIdx.x & 63;
    int tok0 = blockIdx.x * 16;

    {
        const float4* src = (const float4*)(hs + (size_t)tok0 * DSZ);
        ((float4*)&shs[0][0])[threadIdx.x] = src[threadIdx.x];
    }
    __syncthreads();

    float acc[4][8] = {};
    for (int k0 = 0; k0 < DSZ; k0 += 16) {
        const float4* src = (const float4*)(wp + (size_t)k0 * DMODEL);
#pragma unroll
        for (int i = 0; i < 8; i++)
            ((float4*)&swp[0][0])[threadIdx.x + i * 256] = src[threadIdx.x + i * 256];
        __syncthreads();
#pragma unroll
        for (int k = 0; k < 16; k++) {
            float bv[8];
#pragma unroll
            for (int j = 0; j < 8; j++) bv[j] = swp[k][lane + 64 * j];
#pragma unroll
            for (int t = 0; t < 4; t++) {
                float av = shs[wv * 4 + t][k0 + k];
#pragma unroll
                for (int j = 0; j < 8; j++) acc[t][j] += av * bv[j];
            }
        }
        __syncthreads();
    }

#pragma unroll
    for (int t = 0; t < 4; t++) {
        int tok = tok0 + wv * 4 + t;
        float u[8];
        float s = 0.f, sq = 0.f;
#pragma unroll
        for (int j = 0; j < 8; j++) {
            int col = lane + 64 * j;
            float v = h[(size_t)tok * DMODEL + col] + acc[t][j] + bp[col];
            u[j] = v;
            s += v; sq += v * v;
        }
#pragma unroll
        for (int o = 32; o > 0; o >>= 1) { s += __shfl_xor(s, o, 64); sq += __shfl_xor(sq, o, 64); }
        float mean = s * (1.f / DMODEL);
        float var = sq * (1.f / DMODEL) - mean * mean;
        float rs = rsqrtf(var + 1e-5f);
        float s2 = 0.f, sq2 = 0.f;
#pragma unroll
        for (int j = 0; j < 8; j++) {
            int col = lane + 64 * j;
            float v = (u[j] - mean) * rs * nmg[col] + nmb[col];
            h[(size_t)tok * DMODEL + col] = v;
            s2 += v; sq2 += v * v;
        }
#pragma unroll
        for (int o = 32; o > 0; o >>= 1) { s2 += __shfl_xor(s2, o, 64); sq2 += __shfl_xor(sq2, o, 64); }
        if (lane == 0) {
            float m2 = s2 * (1.f / DMODEL);
            float v2 = sq2 * (1.f / DMODEL) - m2 * m2;
            mu[tok] = m2;
            rstd[tok] = rsqrtf(v2 + 1e-5f);
        }
    }
}

// ---------------- heads on h[:, -1, :] (f32) ----------------
__global__ __launch_bounds__(64) void heads_k(const float* __restrict__ h,
                                              const float* hd15_w, const float* hd15_b,
                                              const float* hd30_w, const float* hd30_b,
                                              const float* hv_w, const float* hv_b,
                                              const float* hreg_w, const float* hreg_b,
                                              const float* hrng_w, const float* hrng_b,
                                              float* __restrict__ out) {
    int b = blockIdx.x;
    int lane = threadIdx.x;
    __shared__ float row[DMODEL];
    const float* hp = h + (size_t)(b * SEQ + SEQ - 1) * DMODEL;
#pragma unroll
    for (int i = 0; i < 8; i++) row[lane + 64 * i] = hp[lane + 64 * i];
    __syncthreads();
#pragma unroll
    for (int i = 0; i < 8; i++) out[448 + b * DMODEL + lane + 64 * i] = row[lane + 64 * i];
    if (lane < 14) {
        const float* w; const float* bb;
        int ncol, j, off;
        if (lane == 0)      { w = hd15_w; bb = hd15_b; ncol = 1; j = 0;         off = 0 + b; }
        else if (lane == 1) { w = hd30_w; bb = hd30_b; ncol = 1; j = 0;         off = 32 + b; }
        else if (lane < 5)  { j = lane - 2;  w = hv_w;   bb = hv_b;   ncol = 3; off = 64 + b * 3 + j; }
        else if (lane < 11) { j = lane - 5;  w = hreg_w; bb = hreg_b; ncol = 6; off = 160 + b * 6 + j; }
        else                { j = lane - 11; w = hrng_w; bb = hrng_b; ncol = 3; off = 352 + b * 3 + j; }
        float s = bb[j];
        for (int k = 0; k < DMODEL; k++) s += row[k] * w[k * ncol + j];
        out[off] = s;
    }
}

extern "C" void kernel_launch(void* const* d_in, const int* in_sizes, int n_in,
                              void* d_out, int out_size, void* d_ws, size_t ws_size,
                              hipStream_t stream) {
    (void)in_sizes; (void)n_in; (void)out_size; (void)ws_size;
    const float* x      = (const float*)d_in[0];
    const int*   rid    = (const int*)d_in[1];
    const float* emb    = (const float*)d_in[2];
    const float* grn_w1 = (const float*)d_in[3];
    const float* grn_b1 = (const float*)d_in[4];
    const float* grn_w2 = (const float*)d_in[5];
    const float* grn_b2 = (const float*)d_in[6];
    const float* in_w   = (const float*)d_in[7];
    const float* in_b   = (const float*)d_in[8];
    const float* ln_g   = (const float*)d_in[9];
    const float* ln_b   = (const float*)d_in[10];
    const float* wi     = (const float*)d_in[11];
    const float* bi     = (const float*)d_in[12];
    const float* wf     = (const float*)d_in[13];
    const float* bf_    = (const float*)d_in[14];
    const float* wz     = (const float*)d_in[15];
    const float* bz     = (const float*)d_in[16];
    const float* wo     = (const float*)d_in[17];
    const float* bo     = (const float*)d_in[18];
    const float* wp     = (const float*)d_in[19];
    const float* bp     = (const float*)d_in[20];
    const float* nm_g   = (const float*)d_in[21];
    const float* nm_b   = (const float*)d_in[22];

    float* out = (float*)d_out;
    char* W = (char*)d_ws;

    // ---- workspace layout (bytes), peak ~223.2 MB < 226,492,416 proven ----
    float* h               = (float*)W;                      // [MTOK][512] f32
    unsigned short* hidden = (unsigned short*)W;             // alias (GRN phase)
    unsigned short* logits = (unsigned short*)(W + 67108864);
    char* RB = W + 134217728;
    unsigned short* xc = (unsigned short*)RB;                // [MTOK][384] bf16 (GRN phase)
    float* gates  = (float*)RB;                              // [MTOK][256] f32 (layer loop)
    float* hsbuf  = (float*)(RB + 67108864);                 // [MTOK][64] f32
    char* RM = W + 218103808;
    float* aggF  = (float*)(RM);
    float* aggL  = (float*)(RM + 262144);
    float* aggS  = (float*)(RM + 524288);
    float* stM   = (float*)(RM + 786432);
    float* stC   = (float*)(RM + 1048576);
    float* mu    = (float*)(RM + 1310720);
    float* rstd  = (float*)(RM + 1572864);
    unsigned short* w1t  = (unsigned short*)(RM + 1835008);  // [512][384]
    unsigned short* w2t  = (unsigned short*)(RM + 2228224);  // [384][512]
    unsigned short* inwt = (unsigned short*)(RM + 2621440);  // [512][352]
    unsigned short* gwtH = (unsigned short*)(RM + 2981888);  // [16][64][512]
    unsigned short* gwtL = (unsigned short*)(RM + 4030464);  // [16][64][512]
    float* gbias         = (float*)(RM + 5079040);           // [4][256]

    // ---- preconvert (every call; graph-safe) ----
    build_xc_k<<<MTOK * 192 / 256, 256, 0, stream>>>(x, rid, emb, xc);
    tconv_k<<<dim3(2, 512), 256, 0, stream>>>(grn_w1, w1t, 382, 512, 384);
    tconv_k<<<dim3(2, 384), 256, 0, stream>>>(grn_w2, w2t, 512, 350, 512);
    tconv_k<<<dim3(2, 512), 256, 0, stream>>>(in_w, inwt, 350, 512, 352);
    tconv_g_k<<<dim3(2, 64, 16), 256, 0, stream>>>(wi, wf, wz, wo, gwtH, gwtL);
    gbias_k<<<1, 1024, 0, stream>>>(bi, bf_, bz, bo, gbias);

    // GEMM0: hidden = elu(xc @ w1t^T + b1), bf16 out
    mgemm_k<0, 0><<<dim3(4, 512), 256, 0, stream>>>(xc, nullptr, w1t, grn_b1, nullptr, hidden,
                                                    nullptr, nullptr, nullptr, nullptr,
                                                    384, 384, 384, 512, 512);
    // GEMM1: logits = hidden @ w2t^T + b2, bf16 out
    mgemm_k<0, 1><<<dim3(3, 512), 256, 0, stream>>>(hidden, nullptr, w2t, grn_b2, nullptr, logits,
                                                    nullptr, nullptr, nullptr, nullptr,
                                                    512, 512, 512, 350, 350);
    // softmax + xw in-place into xc + weights last row
    softmax_xw_k<<<MTOK / 4, 256, 0, stream>>>(logits, xc, out + 16832);
    // GEMM2: h = xw @ inwt^T + in_b, f32 out
    mgemm_k<0, 3><<<dim3(4, 512), 256, 0, stream>>>(xc, nullptr, inwt, in_b, h, nullptr,
                                                    nullptr, nullptr, nullptr, nullptr,
                                                    384, 352, 352, 512, 512);
    // layer-0 LN stats
    ln_stats_k<<<MTOK / 4, 256, 0, stream>>>(h, mu, rstd);

    for (int l = 0; l < NLAYER; l++) {
        // gates = act(LN(h) @ W_g + b_g) with hi/lo-split MFMA (near-f32)
        ggemm_k<<<dim3(2, 1024), 256, 0, stream>>>(h,
                                                   gwtH + (size_t)l * 131072,
                                                   gwtL + (size_t)l * 131072,
                                                   gbias + l * 256,
                                                   mu, rstd,
                                                   ln_g + l * DMODEL, ln_b + l * DMODEL,
                                                   gates);
        seg_agg_k<<<BATCH * 8, 256, 0, stream>>>(gates, aggF, aggL, aggS);
        chunk_scan_k<<<BATCH, 64, 0, stream>>>(aggF, aggL, aggS, stM, stC);
        replay_k<<<BATCH * 8, 256, 0, stream>>>(gates, stM, stC, hsbuf);

        outproj_k<<<MTOK / 16, 256, 0, stream>>>(hsbuf,
                                                 wp + (size_t)l * DSZ * DMODEL,
                                                 bp + l * DMODEL,
                                                 nm_g + l * DMODEL,
                                                 nm_b + l * DMODEL,
                                                 h, mu, rstd);
    }

    heads_k<<<BATCH, 64, 0, stream>>>(h,
                                      (const float*)d_in[23], (const float*)d_in[24],
                                      (const float*)d_in[25], (const float*)d_in[26],
                                      (const float*)d_in[27], (const float*)d_in[28],
                                      (const float*)d_in[29], (const float*)d_in[30],
                                      (const float*)d_in[31], (const float*)d_in[32],
                                      out);
}